// Round 2
// baseline (756.188 us; speedup 1.0000x reference)
//
#include <hip/hip_runtime.h>
#include <math.h>

#define N_NODES 100000
#define N_EDGES 1600000
#define IN_FEAT 16
#define OUT_FEAT 16
#define HEADS 6
#define HF (HEADS * OUT_FEAT)          // 96
#define E_TOT (N_EDGES + N_NODES)      // 1,700,000 (self-loops appended)

// ---------------------------------------------------------------------------
// Kernel A: x = data @ W  (per node, per head), plus attention logits
//   a_src[n,h] = sum_f x[n,h,f]*att_src[h,f];  a_dst likewise.
// One thread per (node, head). W + att vectors staged in LDS (6.7 KB).
// ---------------------------------------------------------------------------
__global__ void node_transform(const float* __restrict__ data,
                               const float* __restrict__ W,
                               const float* __restrict__ att_src,
                               const float* __restrict__ att_dst,
                               float* __restrict__ x,
                               float* __restrict__ a_src,
                               float* __restrict__ a_dst) {
    __shared__ float sW[IN_FEAT * HF];
    __shared__ float sAs[HF], sAd[HF];
    for (int i = threadIdx.x; i < IN_FEAT * HF; i += blockDim.x) sW[i] = W[i];
    for (int i = threadIdx.x; i < HF; i += blockDim.x) { sAs[i] = att_src[i]; sAd[i] = att_dst[i]; }
    __syncthreads();

    int gid = blockIdx.x * blockDim.x + threadIdx.x;
    int n = gid / HEADS;
    int h = gid % HEADS;
    if (n >= N_NODES) return;

    float dv[IN_FEAT];
    const float4* dp = (const float4*)(data + (size_t)n * IN_FEAT);
#pragma unroll
    for (int q = 0; q < 4; q++) {
        float4 v = dp[q];
        dv[q*4+0] = v.x; dv[q*4+1] = v.y; dv[q*4+2] = v.z; dv[q*4+3] = v.w;
    }

    float out[OUT_FEAT];
#pragma unroll
    for (int f = 0; f < OUT_FEAT; f++) out[f] = 0.f;
#pragma unroll
    for (int k = 0; k < IN_FEAT; k++) {
        float dk = dv[k];
        const float* wrow = &sW[k * HF + h * OUT_FEAT];
#pragma unroll
        for (int f = 0; f < OUT_FEAT; f++) out[f] = fmaf(dk, wrow[f], out[f]);
    }

    float as = 0.f, ad = 0.f;
#pragma unroll
    for (int f = 0; f < OUT_FEAT; f++) {
        as = fmaf(out[f], sAs[h * OUT_FEAT + f], as);
        ad = fmaf(out[f], sAd[h * OUT_FEAT + f], ad);
    }

    float4* xp = (float4*)(x + (size_t)n * HF + h * OUT_FEAT);
#pragma unroll
    for (int q = 0; q < 4; q++)
        xp[q] = make_float4(out[q*4+0], out[q*4+1], out[q*4+2], out[q*4+3]);
    a_src[n * HEADS + h] = as;
    a_dst[n * HEADS + h] = ad;
}

// ---------------------------------------------------------------------------
// Kernel B: softmax denominator per (dst, head).
// Max-subtraction is dropped: exp(e)/sum(exp(e)) is mathematically identical
// and |e| is bounded (~5) for this problem, so no overflow.
// One thread per edge; 6 atomicAdds.
// ---------------------------------------------------------------------------
__global__ void edge_sum(const int* __restrict__ esrc,
                         const int* __restrict__ edst,
                         const float* __restrict__ a_src,
                         const float* __restrict__ a_dst,
                         float* __restrict__ seg_sum) {
    int i = blockIdx.x * blockDim.x + threadIdx.x;
    if (i >= E_TOT) return;
    int s, d;
    if (i < N_EDGES) { s = esrc[i]; d = edst[i]; }
    else             { s = d = i - N_EDGES; }
#pragma unroll
    for (int h = 0; h < HEADS; h++) {
        float e = a_src[s * HEADS + h] + a_dst[d * HEADS + h];
        e = e > 0.f ? e : 0.2f * e;            // leaky relu
        atomicAdd(&seg_sum[d * HEADS + h], __expf(e));
    }
}

// ---------------------------------------------------------------------------
// Kernel C: aggregate. 16 threads per edge (thread f = output feature f).
// partial[f] = sum_h x[s,h,f] * alpha[h]  -> one atomicAdd per (edge, f).
// Coord message uses sum_h alpha -> 2 atomicAdds per edge.
// ---------------------------------------------------------------------------
__global__ void edge_aggregate(const int* __restrict__ esrc,
                               const int* __restrict__ edst,
                               const float* __restrict__ data,
                               const float* __restrict__ x,
                               const float* __restrict__ a_src,
                               const float* __restrict__ a_dst,
                               const float* __restrict__ seg_sum,
                               float* __restrict__ feat_acc,
                               float* __restrict__ coord_acc) {
    long long gid = (long long)blockIdx.x * blockDim.x + threadIdx.x;
    int i = (int)(gid >> 4);
    int f = (int)(gid & 15);
    if (i >= E_TOT) return;
    int s, d;
    if (i < N_EDGES) { s = esrc[i]; d = edst[i]; }
    else             { s = d = i - N_EDGES; }

    float alpha[HEADS];
    float suma = 0.f;
#pragma unroll
    for (int h = 0; h < HEADS; h++) {
        float e = a_src[s * HEADS + h] + a_dst[d * HEADS + h];
        e = e > 0.f ? e : 0.2f * e;
        float w = __expf(e);
        float a = w / (seg_sum[d * HEADS + h] + 1e-16f);
        alpha[h] = a;
        suma += a;
    }

    float p = 0.f;
#pragma unroll
    for (int h = 0; h < HEADS; h++)
        p = fmaf(x[(size_t)s * HF + h * OUT_FEAT + f], alpha[h], p);
    atomicAdd(&feat_acc[(size_t)d * OUT_FEAT + f], p);

    if (f < 2)
        atomicAdd(&coord_acc[d * 2 + f], data[(size_t)s * IN_FEAT + f] * suma);
}

// ---------------------------------------------------------------------------
// Kernel D: finalize. feat = selu(mean_h + bias); coord = 0.2*mean_h with
// boundary overrides (data[:,0/1] == 0.0 / 1.0 exact compares).
// One thread per (node, feature).
// ---------------------------------------------------------------------------
__global__ void finalize(const float* __restrict__ data,
                         const float* __restrict__ feat_acc,
                         const float* __restrict__ coord_acc,
                         const float* __restrict__ bias,
                         float* __restrict__ out) {
    int gid = blockIdx.x * blockDim.x + threadIdx.x;
    int n = gid / OUT_FEAT;
    int f = gid % OUT_FEAT;
    if (n >= N_NODES) return;

    float v = feat_acc[(size_t)n * OUT_FEAT + f] * (1.f / 6.f) + bias[f];
    const float sc = 1.0507009873554805f;
    const float al = 1.6732632423543772f;
    v = v > 0.f ? sc * v : sc * al * (__expf(v) - 1.f);
    out[2 * N_NODES + (size_t)n * OUT_FEAT + f] = v;

    if (f < 2) {
        float c = coord_acc[n * 2 + f] * (0.2f / 6.f);
        float key = data[(size_t)n * IN_FEAT + f];
        if (key == 1.0f)      c = 1.0f;
        else if (key == 0.0f) c = 0.0f;
        out[n * 2 + f] = c;
    }
}

// ---------------------------------------------------------------------------
// Workspace layout (floats):
//   [0, 600000)            seg_sum   (N*6)      } zeroed each launch
//   [600000, 2200000)      feat_acc  (N*16)     } (one 9.6 MB memset)
//   [2200000, 2400000)     coord_acc (N*2)      }
//   [2400000, 12000000)    x         (N*96)
//   [12000000, 12600000)   a_src     (N*6)
//   [12600000, 13200000)   a_dst     (N*6)
// Total 13.2M floats = 52.8 MB.
// ---------------------------------------------------------------------------
extern "C" void kernel_launch(void* const* d_in, const int* in_sizes, int n_in,
                              void* d_out, int out_size, void* d_ws, size_t ws_size,
                              hipStream_t stream) {
    const float* data    = (const float*)d_in[0];
    const int*   eidx    = (const int*)d_in[1];      // int32 on device (harness converts integer inputs)
    const float* W       = (const float*)d_in[2];
    const float* att_src = (const float*)d_in[3];
    const float* att_dst = (const float*)d_in[4];
    const float* bias    = (const float*)d_in[5];
    float*       out     = (float*)d_out;
    float*       ws      = (float*)d_ws;

    float* seg_sum   = ws;
    float* feat_acc  = ws + 600000;
    float* coord_acc = ws + 2200000;
    float* x         = ws + 2400000;
    float* a_src     = ws + 12000000;
    float* a_dst     = ws + 12600000;

    hipMemsetAsync(d_ws, 0, 2400000 * sizeof(float), stream);

    {
        int total = N_NODES * HEADS;
        node_transform<<<(total + 255) / 256, 256, 0, stream>>>(
            data, W, att_src, att_dst, x, a_src, a_dst);
    }
    {
        edge_sum<<<(E_TOT + 255) / 256, 256, 0, stream>>>(
            eidx, eidx + N_EDGES, a_src, a_dst, seg_sum);
    }
    {
        long long total = (long long)E_TOT * 16;
        edge_aggregate<<<(int)((total + 255) / 256), 256, 0, stream>>>(
            eidx, eidx + N_EDGES, data, x, a_src, a_dst, seg_sum,
            feat_acc, coord_acc);
    }
    {
        int total = N_NODES * OUT_FEAT;
        finalize<<<(total + 255) / 256, 256, 0, stream>>>(
            data, feat_acc, coord_acc, bias, out);
    }
}

// Round 3
// 362.518 us; speedup vs baseline: 2.0859x; 2.0859x over previous
//
#include <hip/hip_runtime.h>
#include <math.h>

#define N_NODES 100000
#define N_EDGES 1600000
#define IN_FEAT 16
#define OUT_FEAT 16
#define HEADS 6
#define HF (HEADS * OUT_FEAT)          // 96
#define E_TOT (N_EDGES + N_NODES)      // 1,700,000 (self-loops appended)

// ---------------------------------------------------------------------------
// Kernel A: x = data @ W  (per node, per head), plus attention logits
// ---------------------------------------------------------------------------
__global__ void node_transform(const float* __restrict__ data,
                               const float* __restrict__ W,
                               const float* __restrict__ att_src,
                               const float* __restrict__ att_dst,
                               float* __restrict__ x,
                               float* __restrict__ a_src,
                               float* __restrict__ a_dst) {
    __shared__ float sW[IN_FEAT * HF];
    __shared__ float sAs[HF], sAd[HF];
    for (int i = threadIdx.x; i < IN_FEAT * HF; i += blockDim.x) sW[i] = W[i];
    for (int i = threadIdx.x; i < HF; i += blockDim.x) { sAs[i] = att_src[i]; sAd[i] = att_dst[i]; }
    __syncthreads();

    int gid = blockIdx.x * blockDim.x + threadIdx.x;
    int n = gid / HEADS;
    int h = gid % HEADS;
    if (n >= N_NODES) return;

    float dv[IN_FEAT];
    const float4* dp = (const float4*)(data + (size_t)n * IN_FEAT);
#pragma unroll
    for (int q = 0; q < 4; q++) {
        float4 v = dp[q];
        dv[q*4+0] = v.x; dv[q*4+1] = v.y; dv[q*4+2] = v.z; dv[q*4+3] = v.w;
    }

    float out[OUT_FEAT];
#pragma unroll
    for (int f = 0; f < OUT_FEAT; f++) out[f] = 0.f;
#pragma unroll
    for (int k = 0; k < IN_FEAT; k++) {
        float dk = dv[k];
        const float* wrow = &sW[k * HF + h * OUT_FEAT];
#pragma unroll
        for (int f = 0; f < OUT_FEAT; f++) out[f] = fmaf(dk, wrow[f], out[f]);
    }

    float as = 0.f, ad = 0.f;
#pragma unroll
    for (int f = 0; f < OUT_FEAT; f++) {
        as = fmaf(out[f], sAs[h * OUT_FEAT + f], as);
        ad = fmaf(out[f], sAd[h * OUT_FEAT + f], ad);
    }

    float4* xp = (float4*)(x + (size_t)n * HF + h * OUT_FEAT);
#pragma unroll
    for (int q = 0; q < 4; q++)
        xp[q] = make_float4(out[q*4+0], out[q*4+1], out[q*4+2], out[q*4+3]);
    a_src[n * HEADS + h] = as;
    a_dst[n * HEADS + h] = ad;
}

// ---------------------------------------------------------------------------
// Kernel B: softmax denominator per (dst, head).
// 8 lanes per edge (lane h = head h, lanes 6,7 idle): the 6 atomics of one
// edge land in one contiguous 24B region -> same-line atomic coalescing.
// (Round-2 profile: 1 thread/edge issued 6 wave-instrs x 64 random lines;
//  WRITE_SIZE showed 32B fabric RMW per atomic. This layout cuts distinct
//  lines per atomic instruction ~6-8x.)
// ---------------------------------------------------------------------------
__global__ void edge_sum(const int* __restrict__ esrc,
                         const int* __restrict__ edst,
                         const float* __restrict__ a_src,
                         const float* __restrict__ a_dst,
                         float* __restrict__ seg_sum) {
    long long gid = (long long)blockIdx.x * blockDim.x + threadIdx.x;
    int i = (int)(gid >> 3);
    int h = (int)(gid & 7);
    if (i >= E_TOT || h >= HEADS) return;
    int s, d;
    if (i < N_EDGES) { s = esrc[i]; d = edst[i]; }
    else             { s = d = i - N_EDGES; }
    float e = a_src[s * HEADS + h] + a_dst[d * HEADS + h];
    e = e > 0.f ? e : 0.2f * e;            // leaky relu
    atomicAdd(&seg_sum[d * HEADS + h], __expf(e));
}

// ---------------------------------------------------------------------------
// Kernel C: aggregate. 16 threads per edge (thread f = output feature f).
// The 16 feat atomics per edge are contiguous (one 64B line) -> coalesce.
// ---------------------------------------------------------------------------
__global__ void edge_aggregate(const int* __restrict__ esrc,
                               const int* __restrict__ edst,
                               const float* __restrict__ data,
                               const float* __restrict__ x,
                               const float* __restrict__ a_src,
                               const float* __restrict__ a_dst,
                               const float* __restrict__ seg_sum,
                               float* __restrict__ feat_acc,
                               float* __restrict__ coord_acc) {
    long long gid = (long long)blockIdx.x * blockDim.x + threadIdx.x;
    int i = (int)(gid >> 4);
    int f = (int)(gid & 15);
    if (i >= E_TOT) return;
    int s, d;
    if (i < N_EDGES) { s = esrc[i]; d = edst[i]; }
    else             { s = d = i - N_EDGES; }

    float alpha[HEADS];
    float suma = 0.f;
#pragma unroll
    for (int h = 0; h < HEADS; h++) {
        float e = a_src[s * HEADS + h] + a_dst[d * HEADS + h];
        e = e > 0.f ? e : 0.2f * e;
        float w = __expf(e);
        float a = w / (seg_sum[d * HEADS + h] + 1e-16f);
        alpha[h] = a;
        suma += a;
    }

    float p = 0.f;
#pragma unroll
    for (int h = 0; h < HEADS; h++)
        p = fmaf(x[(size_t)s * HF + h * OUT_FEAT + f], alpha[h], p);
    atomicAdd(&feat_acc[(size_t)d * OUT_FEAT + f], p);

    if (f < 2)
        atomicAdd(&coord_acc[d * 2 + f], data[(size_t)s * IN_FEAT + f] * suma);
}

// ---------------------------------------------------------------------------
// Kernel D: finalize.
// ---------------------------------------------------------------------------
__global__ void finalize(const float* __restrict__ data,
                         const float* __restrict__ feat_acc,
                         const float* __restrict__ coord_acc,
                         const float* __restrict__ bias,
                         float* __restrict__ out) {
    int gid = blockIdx.x * blockDim.x + threadIdx.x;
    int n = gid / OUT_FEAT;
    int f = gid % OUT_FEAT;
    if (n >= N_NODES) return;

    float v = feat_acc[(size_t)n * OUT_FEAT + f] * (1.f / 6.f) + bias[f];
    const float sc = 1.0507009873554805f;
    const float al = 1.6732632423543772f;
    v = v > 0.f ? sc * v : sc * al * (__expf(v) - 1.f);
    out[2 * N_NODES + (size_t)n * OUT_FEAT + f] = v;

    if (f < 2) {
        float c = coord_acc[n * 2 + f] * (0.2f / 6.f);
        float key = data[(size_t)n * IN_FEAT + f];
        if (key == 1.0f)      c = 1.0f;
        else if (key == 0.0f) c = 0.0f;
        out[n * 2 + f] = c;
    }
}

// ---------------------------------------------------------------------------
// Workspace layout (floats):
//   [0, 600000)            seg_sum   (N*6)      } zeroed each launch
//   [600000, 2200000)      feat_acc  (N*16)     }
//   [2200000, 2400000)     coord_acc (N*2)      }
//   [2400000, 12000000)    x         (N*96)
//   [12000000, 12600000)   a_src     (N*6)
//   [12600000, 13200000)   a_dst     (N*6)
// ---------------------------------------------------------------------------
extern "C" void kernel_launch(void* const* d_in, const int* in_sizes, int n_in,
                              void* d_out, int out_size, void* d_ws, size_t ws_size,
                              hipStream_t stream) {
    const float* data    = (const float*)d_in[0];
    const int*   eidx    = (const int*)d_in[1];      // int32 on device
    const float* W       = (const float*)d_in[2];
    const float* att_src = (const float*)d_in[3];
    const float* att_dst = (const float*)d_in[4];
    const float* bias    = (const float*)d_in[5];
    float*       out     = (float*)d_out;
    float*       ws      = (float*)d_ws;

    float* seg_sum   = ws;
    float* feat_acc  = ws + 600000;
    float* coord_acc = ws + 2200000;
    float* x         = ws + 2400000;
    float* a_src     = ws + 12000000;
    float* a_dst     = ws + 12600000;

    hipMemsetAsync(d_ws, 0, 2400000 * sizeof(float), stream);

    {
        int total = N_NODES * HEADS;
        node_transform<<<(total + 255) / 256, 256, 0, stream>>>(
            data, W, att_src, att_dst, x, a_src, a_dst);
    }
    {
        long long total = (long long)E_TOT * 8;
        edge_sum<<<(int)((total + 255) / 256), 256, 0, stream>>>(
            eidx, eidx + N_EDGES, a_src, a_dst, seg_sum);
    }
    {
        long long total = (long long)E_TOT * 16;
        edge_aggregate<<<(int)((total + 255) / 256), 256, 0, stream>>>(
            eidx, eidx + N_EDGES, data, x, a_src, a_dst, seg_sum,
            feat_acc, coord_acc);
    }
    {
        int total = N_NODES * OUT_FEAT;
        finalize<<<(total + 255) / 256, 256, 0, stream>>>(
            data, feat_acc, coord_acc, bias, out);
    }
}

// Round 4
// 325.818 us; speedup vs baseline: 2.3209x; 1.1126x over previous
//
#include <hip/hip_runtime.h>
#include <math.h>

#define N_NODES 100000
#define N_EDGES 1600000
#define IN_FEAT 16
#define OUT_FEAT 16
#define HEADS 6
#define HF (HEADS * OUT_FEAT)          // 96
#define E_TOT (N_EDGES + N_NODES)      // 1,700,000 (self-loops appended)

// bf16 round-to-nearest-even (ignores NaN, fine for this data)
static __device__ __forceinline__ unsigned short f2bf(float x) {
    unsigned int u = __float_as_uint(x);
    u = (u + 0x7FFFu + ((u >> 16) & 1u)) >> 16;
    return (unsigned short)u;
}
static __device__ __forceinline__ float bf2f(unsigned short b) {
    return __uint_as_float(((unsigned int)b) << 16);
}

// ---------------------------------------------------------------------------
// Kernel A: x = data @ W  (per node, per head), plus attention logits.
// x is stored as bf16 (halves the 653 MB gather traffic in edge_aggregate;
// error budget: ~0.002 absmax vs 0.016 threshold).
// ---------------------------------------------------------------------------
__global__ void node_transform(const float* __restrict__ data,
                               const float* __restrict__ W,
                               const float* __restrict__ att_src,
                               const float* __restrict__ att_dst,
                               unsigned short* __restrict__ xb,
                               float* __restrict__ a_src,
                               float* __restrict__ a_dst) {
    __shared__ float sW[IN_FEAT * HF];
    __shared__ float sAs[HF], sAd[HF];
    for (int i = threadIdx.x; i < IN_FEAT * HF; i += blockDim.x) sW[i] = W[i];
    for (int i = threadIdx.x; i < HF; i += blockDim.x) { sAs[i] = att_src[i]; sAd[i] = att_dst[i]; }
    __syncthreads();

    int gid = blockIdx.x * blockDim.x + threadIdx.x;
    int n = gid / HEADS;
    int h = gid % HEADS;
    if (n >= N_NODES) return;

    float dv[IN_FEAT];
    const float4* dp = (const float4*)(data + (size_t)n * IN_FEAT);
#pragma unroll
    for (int q = 0; q < 4; q++) {
        float4 v = dp[q];
        dv[q*4+0] = v.x; dv[q*4+1] = v.y; dv[q*4+2] = v.z; dv[q*4+3] = v.w;
    }

    float out[OUT_FEAT];
#pragma unroll
    for (int f = 0; f < OUT_FEAT; f++) out[f] = 0.f;
#pragma unroll
    for (int k = 0; k < IN_FEAT; k++) {
        float dk = dv[k];
        const float* wrow = &sW[k * HF + h * OUT_FEAT];
#pragma unroll
        for (int f = 0; f < OUT_FEAT; f++) out[f] = fmaf(dk, wrow[f], out[f]);
    }

    float as = 0.f, ad = 0.f;
#pragma unroll
    for (int f = 0; f < OUT_FEAT; f++) {
        as = fmaf(out[f], sAs[h * OUT_FEAT + f], as);
        ad = fmaf(out[f], sAd[h * OUT_FEAT + f], ad);
    }

    // pack 16 bf16 = 32 B = two uint4 stores
    unsigned int pk[8];
#pragma unroll
    for (int q = 0; q < 8; q++)
        pk[q] = (unsigned int)f2bf(out[2*q]) | ((unsigned int)f2bf(out[2*q+1]) << 16);
    uint4* xp = (uint4*)(xb + (size_t)n * HF + h * OUT_FEAT);
    xp[0] = make_uint4(pk[0], pk[1], pk[2], pk[3]);
    xp[1] = make_uint4(pk[4], pk[5], pk[6], pk[7]);

    a_src[n * HEADS + h] = as;
    a_dst[n * HEADS + h] = ad;
}

// ---------------------------------------------------------------------------
// Kernel B: softmax denominator per (dst, head).
// 8 lanes per edge (lane h = head h): the 6 atomics of one edge land in one
// contiguous 24B region -> same-line atomic coalescing (R2->R3: 497->~100us).
// ---------------------------------------------------------------------------
__global__ void edge_sum(const int* __restrict__ esrc,
                         const int* __restrict__ edst,
                         const float* __restrict__ a_src,
                         const float* __restrict__ a_dst,
                         float* __restrict__ seg_sum) {
    long long gid = (long long)blockIdx.x * blockDim.x + threadIdx.x;
    int i = (int)(gid >> 3);
    int h = (int)(gid & 7);
    if (i >= E_TOT || h >= HEADS) return;
    int s, d;
    if (i < N_EDGES) { s = esrc[i]; d = edst[i]; }
    else             { s = d = i - N_EDGES; }
    float e = a_src[s * HEADS + h] + a_dst[d * HEADS + h];
    e = e > 0.f ? e : 0.2f * e;            // leaky relu
    atomicAdd(&seg_sum[d * HEADS + h], __expf(e));
}

// ---------------------------------------------------------------------------
// Kernel C: aggregate. 16 lanes per edge (lane f = output feature f).
// Lane-specialized alpha: lane h<6 computes exp/rcp for head h once,
// __shfl(...,h,16) broadcasts -> 6 exp + 6 rcp per edge instead of 96+96.
// x gathered as bf16 (32 B per (edge,head) across the 16-lane group).
// ---------------------------------------------------------------------------
__global__ void edge_aggregate(const int* __restrict__ esrc,
                               const int* __restrict__ edst,
                               const float* __restrict__ data,
                               const unsigned short* __restrict__ xb,
                               const float* __restrict__ a_src,
                               const float* __restrict__ a_dst,
                               const float* __restrict__ seg_sum,
                               float* __restrict__ feat_acc,
                               float* __restrict__ coord_acc) {
    long long gid = (long long)blockIdx.x * blockDim.x + threadIdx.x;
    int i = (int)(gid >> 4);
    int f = (int)(gid & 15);
    if (i >= E_TOT) return;
    int s, d;
    if (i < N_EDGES) { s = esrc[i]; d = edst[i]; }
    else             { s = d = i - N_EDGES; }

    float aj = 0.f;
    if (f < HEADS) {
        float e = a_src[s * HEADS + f] + a_dst[d * HEADS + f];
        e = e > 0.f ? e : 0.2f * e;
        aj = __expf(e) * __builtin_amdgcn_rcpf(seg_sum[d * HEADS + f] + 1e-16f);
    }

    const unsigned short* xr = xb + (size_t)s * HF + f;
    float suma = 0.f, p = 0.f;
#pragma unroll
    for (int h = 0; h < HEADS; h++) {
        float ah = __shfl(aj, h, 16);
        suma += ah;
        p = fmaf(bf2f(xr[h * OUT_FEAT]), ah, p);
    }

    atomicAdd(&feat_acc[(size_t)d * OUT_FEAT + f], p);
    if (f < 2)
        atomicAdd(&coord_acc[d * 2 + f], data[(size_t)s * IN_FEAT + f] * suma);
}

// ---------------------------------------------------------------------------
// Kernel D: finalize.
// ---------------------------------------------------------------------------
__global__ void finalize(const float* __restrict__ data,
                         const float* __restrict__ feat_acc,
                         const float* __restrict__ coord_acc,
                         const float* __restrict__ bias,
                         float* __restrict__ out) {
    int gid = blockIdx.x * blockDim.x + threadIdx.x;
    int n = gid / OUT_FEAT;
    int f = gid % OUT_FEAT;
    if (n >= N_NODES) return;

    float v = feat_acc[(size_t)n * OUT_FEAT + f] * (1.f / 6.f) + bias[f];
    const float sc = 1.0507009873554805f;
    const float al = 1.6732632423543772f;
    v = v > 0.f ? sc * v : sc * al * (__expf(v) - 1.f);
    out[2 * N_NODES + (size_t)n * OUT_FEAT + f] = v;

    if (f < 2) {
        float c = coord_acc[n * 2 + f] * (0.2f / 6.f);
        float key = data[(size_t)n * IN_FEAT + f];
        if (key == 1.0f)      c = 1.0f;
        else if (key == 0.0f) c = 0.0f;
        out[n * 2 + f] = c;
    }
}

// ---------------------------------------------------------------------------
// Workspace layout (float offsets; x region reinterpreted as bf16):
//   [0, 600000)            seg_sum   (N*6)      } zeroed each launch
//   [600000, 2200000)      feat_acc  (N*16)     }
//   [2200000, 2400000)     coord_acc (N*2)      }
//   [2400000, 12000000)    x         (N*96 bf16 = 19.2 MB, region 38.4 MB)
//   [12000000, 12600000)   a_src     (N*6)
//   [12600000, 13200000)   a_dst     (N*6)
// ---------------------------------------------------------------------------
extern "C" void kernel_launch(void* const* d_in, const int* in_sizes, int n_in,
                              void* d_out, int out_size, void* d_ws, size_t ws_size,
                              hipStream_t stream) {
    const float* data    = (const float*)d_in[0];
    const int*   eidx    = (const int*)d_in[1];      // int32 on device
    const float* W       = (const float*)d_in[2];
    const float* att_src = (const float*)d_in[3];
    const float* att_dst = (const float*)d_in[4];
    const float* bias    = (const float*)d_in[5];
    float*       out     = (float*)d_out;
    float*       ws      = (float*)d_ws;

    float*          seg_sum   = ws;
    float*          feat_acc  = ws + 600000;
    float*          coord_acc = ws + 2200000;
    unsigned short* xb        = (unsigned short*)(ws + 2400000);
    float*          a_src     = ws + 12000000;
    float*          a_dst     = ws + 12600000;

    hipMemsetAsync(d_ws, 0, 2400000 * sizeof(float), stream);

    {
        int total = N_NODES * HEADS;
        node_transform<<<(total + 255) / 256, 256, 0, stream>>>(
            data, W, att_src, att_dst, xb, a_src, a_dst);
    }
    {
        long long total = (long long)E_TOT * 8;
        edge_sum<<<(int)((total + 255) / 256), 256, 0, stream>>>(
            eidx, eidx + N_EDGES, a_src, a_dst, seg_sum);
    }
    {
        long long total = (long long)E_TOT * 16;
        edge_aggregate<<<(int)((total + 255) / 256), 256, 0, stream>>>(
            eidx, eidx + N_EDGES, data, xb, a_src, a_dst, seg_sum,
            feat_acc, coord_acc);
    }
    {
        int total = N_NODES * OUT_FEAT;
        finalize<<<(total + 255) / 256, 256, 0, stream>>>(
            data, feat_acc, coord_acc, bias, out);
    }
}

// Round 5
// 311.902 us; speedup vs baseline: 2.4244x; 1.0446x over previous
//
#include <hip/hip_runtime.h>
#include <math.h>

#define N_NODES 100000
#define N_EDGES 1600000
#define IN_FEAT 16
#define OUT_FEAT 16
#define HEADS 6
#define HF (HEADS * OUT_FEAT)          // 96
#define E_TOT (N_EDGES + N_NODES)      // 1,700,000 (self-loops appended)

// ---------------------------------------------------------------------------
// Kernel A: attention logits only (x is no longer materialized — the
// aggregate kernel recomputes x[s] from the 64B data row, which is cheaper
// than gathering a 192B x row from a >L2-sized array).
// One thread per (node, head).
// ---------------------------------------------------------------------------
__global__ void node_transform(const float* __restrict__ data,
                               const float* __restrict__ W,
                               const float* __restrict__ att_src,
                               const float* __restrict__ att_dst,
                               float* __restrict__ a_src,
                               float* __restrict__ a_dst) {
    __shared__ float sW[IN_FEAT * HF];
    __shared__ float sAs[HF], sAd[HF];
    for (int i = threadIdx.x; i < IN_FEAT * HF; i += blockDim.x) sW[i] = W[i];
    for (int i = threadIdx.x; i < HF; i += blockDim.x) { sAs[i] = att_src[i]; sAd[i] = att_dst[i]; }
    __syncthreads();

    int gid = blockIdx.x * blockDim.x + threadIdx.x;
    int n = gid / HEADS;
    int h = gid % HEADS;
    if (n >= N_NODES) return;

    float dv[IN_FEAT];
    const float4* dp = (const float4*)(data + (size_t)n * IN_FEAT);
#pragma unroll
    for (int q = 0; q < 4; q++) {
        float4 v = dp[q];
        dv[q*4+0] = v.x; dv[q*4+1] = v.y; dv[q*4+2] = v.z; dv[q*4+3] = v.w;
    }

    float out[OUT_FEAT];
#pragma unroll
    for (int f = 0; f < OUT_FEAT; f++) out[f] = 0.f;
#pragma unroll
    for (int k = 0; k < IN_FEAT; k++) {
        float dk = dv[k];
        const float* wrow = &sW[k * HF + h * OUT_FEAT];
#pragma unroll
        for (int f = 0; f < OUT_FEAT; f++) out[f] = fmaf(dk, wrow[f], out[f]);
    }

    float as = 0.f, ad = 0.f;
#pragma unroll
    for (int f = 0; f < OUT_FEAT; f++) {
        as = fmaf(out[f], sAs[h * OUT_FEAT + f], as);
        ad = fmaf(out[f], sAd[h * OUT_FEAT + f], ad);
    }
    a_src[n * HEADS + h] = as;
    a_dst[n * HEADS + h] = ad;
}

// ---------------------------------------------------------------------------
// Kernel B: softmax denominator per (dst, head).
// 8 lanes per edge (lane h = head h): the 6 atomics of one edge land in one
// contiguous 24B region -> same-line atomic coalescing.
// All gathered arrays (a_src/a_dst 2.4 MB) are L2/L3-resident.
// ---------------------------------------------------------------------------
__global__ void edge_sum(const int* __restrict__ esrc,
                         const int* __restrict__ edst,
                         const float* __restrict__ a_src,
                         const float* __restrict__ a_dst,
                         float* __restrict__ seg_sum) {
    long long gid = (long long)blockIdx.x * blockDim.x + threadIdx.x;
    int i = (int)(gid >> 3);
    int h = (int)(gid & 7);
    if (i >= E_TOT || h >= HEADS) return;
    int s, d;
    if (i < N_EDGES) { s = esrc[i]; d = edst[i]; }
    else             { s = d = i - N_EDGES; }
    float e = a_src[s * HEADS + h] + a_dst[d * HEADS + h];
    e = e > 0.f ? e : 0.2f * e;            // leaky relu
    atomicAdd(&seg_sum[d * HEADS + h], __expf(e));
}

// ---------------------------------------------------------------------------
// Kernel C: aggregate, gather-free on x.
// 16 lanes per edge; grid-stride over edges. Lane f caches the 6 W columns
// W[:, h*16+f] in 96 VGPRs (static unrolled indices -> stays in registers).
// Per edge: fetch data[s] row (1 line, 6.4 MB array = L2/L3-resident),
// recompute x[s,h,f] with 96 FMAs, alpha via lane-specialized exp + shfl,
// one 16-lane coalesced atomic line to feat_acc, 2-lane atomic to coord.
// HBM fetch/edge drops from ~320B (R4) to ~8B of edge index + cache misses.
// ---------------------------------------------------------------------------
__global__ void edge_aggregate(const int* __restrict__ esrc,
                               const int* __restrict__ edst,
                               const float* __restrict__ data,
                               const float* __restrict__ W,
                               const float* __restrict__ a_src,
                               const float* __restrict__ a_dst,
                               const float* __restrict__ seg_sum,
                               float* __restrict__ feat_acc,
                               float* __restrict__ coord_acc) {
    const int tid = blockIdx.x * blockDim.x + threadIdx.x;
    const int f = tid & 15;
    const int ngroups = (gridDim.x * blockDim.x) >> 4;

    // Per-lane W column cache: wreg[h*16+k] = W[k][h*16+f].
    float wreg[96];
#pragma unroll
    for (int h = 0; h < HEADS; h++)
#pragma unroll
        for (int k = 0; k < IN_FEAT; k++)
            wreg[h * 16 + k] = W[k * HF + h * OUT_FEAT + f];

    for (int i = tid >> 4; i < E_TOT; i += ngroups) {
        int s, d;
        if (i < N_EDGES) { s = esrc[i]; d = edst[i]; }
        else             { s = d = i - N_EDGES; }

        // Recompute x[s, h, f] for all 6 heads from the data row.
        float xh[HEADS];
#pragma unroll
        for (int h = 0; h < HEADS; h++) xh[h] = 0.f;
        float c0 = 0.f, c1 = 0.f;
        const float4* dp = (const float4*)(data + (size_t)s * IN_FEAT);
#pragma unroll
        for (int q = 0; q < 4; q++) {
            float4 v = dp[q];
            if (q == 0) { c0 = v.x; c1 = v.y; }
#pragma unroll
            for (int h = 0; h < HEADS; h++) {
                xh[h] = fmaf(v.x, wreg[h * 16 + q * 4 + 0], xh[h]);
                xh[h] = fmaf(v.y, wreg[h * 16 + q * 4 + 1], xh[h]);
                xh[h] = fmaf(v.z, wreg[h * 16 + q * 4 + 2], xh[h]);
                xh[h] = fmaf(v.w, wreg[h * 16 + q * 4 + 3], xh[h]);
            }
        }

        // Lane-specialized alpha (lane h<6 computes head h).
        float aj = 0.f;
        if (f < HEADS) {
            float e = a_src[s * HEADS + f] + a_dst[d * HEADS + f];
            e = e > 0.f ? e : 0.2f * e;
            aj = __expf(e) * __builtin_amdgcn_rcpf(seg_sum[d * HEADS + f] + 1e-16f);
        }

        float suma = 0.f, p = 0.f;
#pragma unroll
        for (int h = 0; h < HEADS; h++) {
            float ah = __shfl(aj, h, 16);
            suma += ah;
            p = fmaf(xh[h], ah, p);
        }

        atomicAdd(&feat_acc[(size_t)d * OUT_FEAT + f], p);
        if (f < 2)
            atomicAdd(&coord_acc[d * 2 + f], (f == 0 ? c0 : c1) * suma);
    }
}

// ---------------------------------------------------------------------------
// Kernel D: finalize.
// ---------------------------------------------------------------------------
__global__ void finalize(const float* __restrict__ data,
                         const float* __restrict__ feat_acc,
                         const float* __restrict__ coord_acc,
                         const float* __restrict__ bias,
                         float* __restrict__ out) {
    int gid = blockIdx.x * blockDim.x + threadIdx.x;
    int n = gid / OUT_FEAT;
    int f = gid % OUT_FEAT;
    if (n >= N_NODES) return;

    float v = feat_acc[(size_t)n * OUT_FEAT + f] * (1.f / 6.f) + bias[f];
    const float sc = 1.0507009873554805f;
    const float al = 1.6732632423543772f;
    v = v > 0.f ? sc * v : sc * al * (__expf(v) - 1.f);
    out[2 * N_NODES + (size_t)n * OUT_FEAT + f] = v;

    if (f < 2) {
        float c = coord_acc[n * 2 + f] * (0.2f / 6.f);
        float key = data[(size_t)n * IN_FEAT + f];
        if (key == 1.0f)      c = 1.0f;
        else if (key == 0.0f) c = 0.0f;
        out[n * 2 + f] = c;
    }
}

// ---------------------------------------------------------------------------
// Workspace layout (floats):
//   [0, 600000)            seg_sum   (N*6)      } zeroed each launch
//   [600000, 2200000)      feat_acc  (N*16)     }
//   [2200000, 2400000)     coord_acc (N*2)      }
//   [2400000, 3000000)     a_src     (N*6)
//   [3000000, 3600000)     a_dst     (N*6)
// Total 3.6M floats = 14.4 MB (was 52.8 — x no longer materialized).
// ---------------------------------------------------------------------------
extern "C" void kernel_launch(void* const* d_in, const int* in_sizes, int n_in,
                              void* d_out, int out_size, void* d_ws, size_t ws_size,
                              hipStream_t stream) {
    const float* data    = (const float*)d_in[0];
    const int*   eidx    = (const int*)d_in[1];      // int32 on device
    const float* W       = (const float*)d_in[2];
    const float* att_src = (const float*)d_in[3];
    const float* att_dst = (const float*)d_in[4];
    const float* bias    = (const float*)d_in[5];
    float*       out     = (float*)d_out;
    float*       ws      = (float*)d_ws;

    float* seg_sum   = ws;
    float* feat_acc  = ws + 600000;
    float* coord_acc = ws + 2200000;
    float* a_src     = ws + 2400000;
    float* a_dst     = ws + 3000000;

    hipMemsetAsync(d_ws, 0, 2400000 * sizeof(float), stream);

    {
        int total = N_NODES * HEADS;
        node_transform<<<(total + 255) / 256, 256, 0, stream>>>(
            data, W, att_src, att_dst, a_src, a_dst);
    }
    {
        long long total = (long long)E_TOT * 8;
        edge_sum<<<(int)((total + 255) / 256), 256, 0, stream>>>(
            eidx, eidx + N_EDGES, a_src, a_dst, seg_sum);
    }
    {
        // Grid-stride: 1024 blocks x 256 = 16384 edge-groups, ~104 edges each
        // (amortizes the one-time 96-VGPR W column load).
        edge_aggregate<<<1024, 256, 0, stream>>>(
            eidx, eidx + N_EDGES, data, W, a_src, a_dst, seg_sum,
            feat_acc, coord_acc);
    }
    {
        int total = N_NODES * OUT_FEAT;
        finalize<<<(total + 255) / 256, 256, 0, stream>>>(
            data, feat_acc, coord_acc, bias, out);
    }
}